// Round 4
// baseline (279.635 us; speedup 1.0000x reference)
//
#include <hip/hip_runtime.h>
#include <hip/hip_bf16.h>

#define IN_FEATS 128
#define OUT_FEATS 64
#define CHUNK 1024        // elements per scan block (256 threads x int4)
#define HB 16             // histogram blocks per key array
#define HIST_THREADS 1024
#define MAX_WORDS 25000   // (N+1)/2 for N=50000 -> 100KB LDS packed u16 histogram

static inline char* align_up(char* p, size_t a) {
    return (char*)(((uintptr_t)p + a - 1) & ~(uintptr_t)(a - 1));
}

// ---------------- per-block LDS histogram (packed u16 pairs), no global atomics ----------------
// blocks 0..HB-1: histogram of dst over slice b ; blocks HB..2HB-1: histogram of src over slice b-HB
__global__ __launch_bounds__(HIST_THREADS)
void hist_kernel(const int* __restrict__ src, const int* __restrict__ dst,
                 unsigned int* __restrict__ partial, int E, int slice, int words) {
    __shared__ unsigned int h[MAX_WORDS];
    int tid = threadIdx.x;
    for (int w = tid; w < words; w += HIST_THREADS) h[w] = 0u;
    __syncthreads();
    int b = blockIdx.x;
    const int* __restrict__ keys = (b < HB) ? dst : src;
    int sb = (b & (HB - 1)) * slice;
    int se = min(sb + slice, E);
    for (int i = sb + tid * 4; i < se; i += HIST_THREADS * 4) {
        if (i + 3 < se) {
            int4 k4 = *reinterpret_cast<const int4*>(keys + i);
            atomicAdd(&h[k4.x >> 1], 1u << ((k4.x & 1) * 16));
            atomicAdd(&h[k4.y >> 1], 1u << ((k4.y & 1) * 16));
            atomicAdd(&h[k4.z >> 1], 1u << ((k4.z & 1) * 16));
            atomicAdd(&h[k4.w >> 1], 1u << ((k4.w & 1) * 16));
        } else {
            for (int j = i; j < se; ++j) {
                int k = keys[j];
                atomicAdd(&h[k >> 1], 1u << ((k & 1) * 16));
            }
        }
    }
    __syncthreads();
    unsigned int* __restrict__ outp = partial + (size_t)b * words;
    for (int w = tid; w < words; w += HIST_THREADS) outp[w] = h[w];
}

// ---------------- sum the 2*HB partial histograms -> cntS, cntD ----------------
__global__ void reduce_kernel(const unsigned int* __restrict__ partial,
                              int* __restrict__ cntS, int* __restrict__ cntD,
                              int N, int words) {
    int w = blockIdx.x * blockDim.x + threadIdx.x;
    if (w >= words) return;
    unsigned int dlo = 0, dhi = 0, slo = 0, shi = 0;
#pragma unroll
    for (int b = 0; b < HB; ++b) {
        unsigned int vd = partial[(size_t)b * words + w];
        unsigned int vs = partial[(size_t)(b + HB) * words + w];
        dlo += vd & 0xffffu; dhi += vd >> 16;
        slo += vs & 0xffffu; shi += vs >> 16;
    }
    int n0 = 2 * w, n1 = 2 * w + 1;
    cntD[n0] = (int)dlo; cntS[n0] = (int)slo;
    if (n1 < N) { cntD[n1] = (int)dhi; cntS[n1] = (int)shi; }
}

// ---------------- scan phase 1: per-block partial sums of cntD ----------------
__global__ void scan_partial(const int* __restrict__ cnt, int* __restrict__ blockSums, int N) {
    __shared__ int red[256];
    int base = blockIdx.x * CHUNK + (int)threadIdx.x * 4;
    int s = 0;
    if (base + 3 < N) {
        int4 v = *reinterpret_cast<const int4*>(cnt + base);
        s = v.x + v.y + v.z + v.w;
    } else {
        for (int i = 0; i < 4; ++i) { int idx = base + i; if (idx < N) s += cnt[idx]; }
    }
    red[threadIdx.x] = s;
    __syncthreads();
    for (int off = 128; off > 0; off >>= 1) {
        if ((int)threadIdx.x < off) red[threadIdx.x] += red[threadIdx.x + off];
        __syncthreads();
    }
    if (threadIdx.x == 0) blockSums[blockIdx.x] = red[0];
}

// ---------------- scan phase 2: one wave scans the block sums ----------------
__global__ void scan_sums(const int* __restrict__ bs, int* __restrict__ boff,
                          int NB, int* __restrict__ rowptr, int N) {
    int lane = threadIdx.x;
    int carry = 0;
    for (int base = 0; base < NB; base += 64) {
        int i = base + lane;
        int orig = (i < NB) ? bs[i] : 0;
        int v = orig;
        for (int off = 1; off < 64; off <<= 1) {
            int t = __shfl_up(v, off);
            if (lane >= off) v += t;
        }
        if (i < NB) boff[i] = carry + v - orig;  // exclusive offset for block i
        carry += __shfl(v, 63);
    }
    if (lane == 0) rowptr[N] = carry;
}

// ---------------- scan phase 3: apply + fused norms ----------------
__global__ void scan_apply(const int* __restrict__ cntD, const int* __restrict__ cntS,
                           const int* __restrict__ boff, int* __restrict__ rowptr,
                           float* __restrict__ normS, float* __restrict__ normD, int N) {
    __shared__ int tsum[256];
    int tid = threadIdx.x;
    int base = blockIdx.x * CHUNK + tid * 4;
    int4 c = make_int4(0, 0, 0, 0);
    bool full = (base + 3 < N);
    if (full) {
        c = *reinterpret_cast<const int4*>(cntD + base);
    } else {
        if (base + 0 < N) c.x = cntD[base + 0];
        if (base + 1 < N) c.y = cntD[base + 1];
        if (base + 2 < N) c.z = cntD[base + 2];
        if (base + 3 < N) c.w = cntD[base + 3];
    }
    int s = c.x + c.y + c.z + c.w;
    tsum[tid] = s;
    __syncthreads();
    for (int off = 1; off < 256; off <<= 1) {
        int t = (tid >= off) ? tsum[tid - off] : 0;
        __syncthreads();
        tsum[tid] += t;
        __syncthreads();
    }
    int excl = tsum[tid] - s + boff[blockIdx.x];
    int r0 = excl, r1 = r0 + c.x, r2 = r1 + c.y, r3 = r2 + c.z;
    if (full) {
        *reinterpret_cast<int4*>(rowptr + base) = make_int4(r0, r1, r2, r3);
        int4 cs = *reinterpret_cast<const int4*>(cntS + base);
        float4 nS = make_float4(rsqrtf(fmaxf((float)cs.x, 1.0f)), rsqrtf(fmaxf((float)cs.y, 1.0f)),
                                rsqrtf(fmaxf((float)cs.z, 1.0f)), rsqrtf(fmaxf((float)cs.w, 1.0f)));
        float4 nD = make_float4(rsqrtf(fmaxf((float)c.x, 1.0f)), rsqrtf(fmaxf((float)c.y, 1.0f)),
                                rsqrtf(fmaxf((float)c.z, 1.0f)), rsqrtf(fmaxf((float)c.w, 1.0f)));
        *reinterpret_cast<float4*>(normS + base) = nS;
        *reinterpret_cast<float4*>(normD + base) = nD;
    } else {
        int r[4] = {r0, r1, r2, r3};
        for (int i = 0; i < 4; ++i) {
            int idx = base + i;
            if (idx < N) {
                rowptr[idx] = r[i];
                normS[idx] = rsqrtf(fmaxf((float)cntS[idx], 1.0f));
                int cd = (i == 0) ? c.x : (i == 1) ? c.y : (i == 2) ? c.z : c.w;
                normD[idx] = rsqrtf(fmaxf((float)cd, 1.0f));
            }
        }
    }
}

// ---------------- CSR bucket fill via LDS cursors (no global atomics) ----------------
// block b re-reads edge slice b; LDS cursor[bin] starts at sum of partials of blocks < b,
// so positions rowptr[bin] + cursor are globally disjoint.
__global__ __launch_bounds__(HIST_THREADS)
void fill_kernel(const int* __restrict__ src, const int* __restrict__ dst,
                 const unsigned int* __restrict__ partial_dst,
                 const int* __restrict__ rowptr,
                 int* __restrict__ csr_src, int E, int slice, int words) {
    __shared__ unsigned int cur[MAX_WORDS];
    int tid = threadIdx.x;
    int b = blockIdx.x;
    for (int w = tid; w < words; w += HIST_THREADS) {
        unsigned int s = 0;
        for (int bp = 0; bp < b; ++bp) s += partial_dst[(size_t)bp * words + w];
        cur[w] = s;   // packed u16 prefixes; per-node totals < 65536 so no cross-half carry
    }
    __syncthreads();
    int sb = b * slice;
    int se = min(sb + slice, E);
    for (int i = sb + tid * 4; i < se; i += HIST_THREADS * 4) {
        if (i + 3 < se) {
            int4 d4 = *reinterpret_cast<const int4*>(dst + i);
            int4 s4 = *reinterpret_cast<const int4*>(src + i);
            int dd[4] = {d4.x, d4.y, d4.z, d4.w};
            int ss[4] = {s4.x, s4.y, s4.z, s4.w};
#pragma unroll
            for (int j = 0; j < 4; ++j) {
                int bin = dd[j];
                unsigned int sh = (unsigned)(bin & 1) * 16u;
                unsigned int old = atomicAdd(&cur[bin >> 1], 1u << sh);
                int off = (int)((old >> sh) & 0xffffu);
                csr_src[rowptr[bin] + off] = ss[j];
            }
        } else {
            for (int j = i; j < se; ++j) {
                int bin = dst[j];
                unsigned int sh = (unsigned)(bin & 1) * 16u;
                unsigned int old = atomicAdd(&cur[bin >> 1], 1u << sh);
                int off = (int)((old >> sh) & 0xffffu);
                csr_src[rowptr[bin] + off] = src[j];
            }
        }
    }
}

// ---------------- projection Y = X @ W  (N x 128 @ 128 x 64) ----------------
__global__ void proj_kernel(const float* __restrict__ X, const float* __restrict__ W,
                            float* __restrict__ Y, int N) {
    __shared__ float w_s[IN_FEATS * OUT_FEATS];
    for (int i = threadIdx.x; i < IN_FEATS * OUT_FEATS; i += 256) w_s[i] = W[i];
    __syncthreads();
    int node = blockIdx.x * 16 + ((int)threadIdx.x >> 4);
    int jj = ((int)threadIdx.x & 15) * 4;
    if (node >= N) return;
    const float* __restrict__ xr = X + (size_t)node * IN_FEATS;
    float4 acc = make_float4(0.f, 0.f, 0.f, 0.f);
#pragma unroll
    for (int k = 0; k < IN_FEATS; ++k) {
        float x = xr[k];
        float4 w = *reinterpret_cast<const float4*>(&w_s[k * OUT_FEATS + jj]);
        acc.x = fmaf(x, w.x, acc.x);
        acc.y = fmaf(x, w.y, acc.y);
        acc.z = fmaf(x, w.z, acc.z);
        acc.w = fmaf(x, w.w, acc.w);
    }
    *reinterpret_cast<float4*>(&Y[(size_t)node * OUT_FEATS + jj]) = acc;
}

// ---------------- gather hop: Yout[i] = epi( sum_{e: dst=i} Yin[src_e] ) ----------------
// one wave per node; 16 lanes x float4 cover the 64-feat row; 4 lane-groups walk 4 edges
// concurrently; 2-round shfl_xor reduce combines the groups. EPI: 0 none, 1 *vec, 2 *vec+bias
template <int EPI>
__global__ void gather_hop(const float* __restrict__ Yin, const int* __restrict__ rowptr,
                           const int* __restrict__ csr_src, float* __restrict__ Yout,
                           const float* __restrict__ vec, const float* __restrict__ bias,
                           int N) {
    int node = blockIdx.x * 4 + ((int)threadIdx.x >> 6);
    int lane = (int)threadIdx.x & 63;
    int g = lane >> 4;              // edge sub-slot 0..3
    int c = (lane & 15) * 4;        // feature offset
    if (node >= N) return;
    int beg = rowptr[node];
    int end = rowptr[node + 1];
    float4 acc = make_float4(0.f, 0.f, 0.f, 0.f);
    for (int k = beg + g; k < end; k += 4) {
        int s = csr_src[k];
        float4 v = *reinterpret_cast<const float4*>(Yin + (size_t)s * OUT_FEATS + c);
        acc.x += v.x; acc.y += v.y; acc.z += v.z; acc.w += v.w;
    }
    acc.x += __shfl_xor(acc.x, 16); acc.y += __shfl_xor(acc.y, 16);
    acc.z += __shfl_xor(acc.z, 16); acc.w += __shfl_xor(acc.w, 16);
    acc.x += __shfl_xor(acc.x, 32); acc.y += __shfl_xor(acc.y, 32);
    acc.z += __shfl_xor(acc.z, 32); acc.w += __shfl_xor(acc.w, 32);
    if (g == 0) {
        if (EPI == 1) {
            float sc = vec[node];
            acc.x *= sc; acc.y *= sc; acc.z *= sc; acc.w *= sc;
        }
        if (EPI == 2) {
            float sc = vec[node];
            float4 bb = *reinterpret_cast<const float4*>(bias + c);
            acc.x = fmaf(acc.x, sc, bb.x); acc.y = fmaf(acc.y, sc, bb.y);
            acc.z = fmaf(acc.z, sc, bb.z); acc.w = fmaf(acc.w, sc, bb.w);
        }
        *reinterpret_cast<float4*>(Yout + (size_t)node * OUT_FEATS + c) = acc;
    }
}

extern "C" void kernel_launch(void* const* d_in, const int* in_sizes, int n_in,
                              void* d_out, int out_size, void* d_ws, size_t ws_size,
                              hipStream_t stream) {
    const float* features = (const float*)d_in[0];
    const int*   src      = (const int*)d_in[1];
    const int*   dst      = (const int*)d_in[2];
    const float* weight   = (const float*)d_in[3];
    const float* bias     = (const float*)d_in[4];

    const int N = in_sizes[0] / IN_FEATS;   // 50000
    const int E = in_sizes[1];              // 640000
    const int NB = (N + CHUNK - 1) / CHUNK;
    const int words = (N + 1) / 2;          // packed u16 words (25000 <= MAX_WORDS)
    const int slice = (((E + HB - 1) / HB) + 3) & ~3;  // 16B-aligned edge slices

    // workspace layout (256B-aligned slabs)
    char* p = (char*)d_ws;
    float* normS   = (float*)p;  p = align_up(p + sizeof(float) * N, 256);
    float* normD   = (float*)p;  p = align_up(p + sizeof(float) * N, 256);
    float* y0      = (float*)p;  p = align_up(p + sizeof(float) * (size_t)N * OUT_FEATS, 256);
    float* y1      = (float*)p;  p = align_up(p + sizeof(float) * (size_t)N * OUT_FEATS, 256);
    int*   cntS    = (int*)p;    p = align_up(p + sizeof(int) * N, 256);
    int*   cntD    = (int*)p;    p = align_up(p + sizeof(int) * N, 256);
    int*   rowptr  = (int*)p;    p = align_up(p + sizeof(int) * (N + 1), 256);
    int*   bsums   = (int*)p;    p = align_up(p + sizeof(int) * NB, 256);
    int*   boff    = (int*)p;    p = align_up(p + sizeof(int) * NB, 256);
    int*   csr_src = (int*)p;    p = align_up(p + sizeof(int) * (size_t)E, 256);

    // partial histograms (2*HB x words u32 = 3.2MB) alias the y1 slab: y1 is only
    // written by hop1, which runs after fill_kernel's last read of the partials.
    unsigned int* partial = (unsigned int*)y1;

    float* out = (float*)d_out;

    // --- CSR build + norms, zero global atomics, zero memsets ---
    hist_kernel<<<2 * HB, HIST_THREADS, 0, stream>>>(src, dst, partial, E, slice, words);
    reduce_kernel<<<(words + 255) / 256, 256, 0, stream>>>(partial, cntS, cntD, N, words);
    scan_partial<<<NB, 256, 0, stream>>>(cntD, bsums, N);
    scan_sums<<<1, 64, 0, stream>>>(bsums, boff, NB, rowptr, N);
    scan_apply<<<NB, 256, 0, stream>>>(cntD, cntS, boff, rowptr, normS, normD, N);
    fill_kernel<<<HB, HIST_THREADS, 0, stream>>>(src, dst, partial, rowptr, csr_src, E, slice, words);

    // --- projection first (A and W commute): y0 = X @ W ---
    proj_kernel<<<(N + 15) / 16, 256, 0, stream>>>(features, weight, y0, N);

    const int hop_blocks = (N + 3) / 4;

    // hop 1: y1 = A y0
    gather_hop<0><<<hop_blocks, 256, 0, stream>>>(y0, rowptr, csr_src, y1, nullptr, nullptr, N);
    // hop 2: y0 = normS .* (A y1)
    gather_hop<1><<<hop_blocks, 256, 0, stream>>>(y1, rowptr, csr_src, y0, normS, nullptr, N);
    // hop 3: out = normD .* (A y0) + bias
    gather_hop<2><<<hop_blocks, 256, 0, stream>>>(y0, rowptr, csr_src, out, normD, bias, N);
}

// Round 5
// 153.282 us; speedup vs baseline: 1.8243x; 1.8243x over previous
//
#include <hip/hip_runtime.h>
#include <hip/hip_bf16.h>

#define IN_FEATS 128
#define OUT_FEATS 64
#define CHUNK 1024        // elements per scan block (256 threads x int4)
#define HB 32             // histogram blocks per key array (64 total)
#define HIST_THREADS 1024
#define MAX_WORDS 25000   // (N+1)/2 for N=50000 -> 100KB LDS packed u16 histogram
#define PROJ_NODES 64
#define XPAD 4            // x_s row stride = IN_FEATS+XPAD floats (16B-aligned, bank-spread)

static inline char* align_up(char* p, size_t a) {
    return (char*)(((uintptr_t)p + a - 1) & ~(uintptr_t)(a - 1));
}

// ---------------- per-block LDS histogram (packed u16 pairs) ----------------
// blocks 0..HB-1: dst slices; blocks HB..2HB-1: src slices
__global__ __launch_bounds__(HIST_THREADS)
void hist_kernel(const int* __restrict__ src, const int* __restrict__ dst,
                 unsigned int* __restrict__ partial, int E, int slice, int words) {
    __shared__ unsigned int h[MAX_WORDS];
    int tid = threadIdx.x;
    for (int w = tid; w < words; w += HIST_THREADS) h[w] = 0u;
    __syncthreads();
    int b = blockIdx.x;
    const int* __restrict__ keys = (b < HB) ? dst : src;
    int sb = (b & (HB - 1)) * slice;
    int se = min(sb + slice, E);
    for (int i = sb + tid * 4; i < se; i += HIST_THREADS * 4) {
        if (i + 3 < se) {
            int4 k4 = *reinterpret_cast<const int4*>(keys + i);
            atomicAdd(&h[k4.x >> 1], 1u << ((k4.x & 1) * 16));
            atomicAdd(&h[k4.y >> 1], 1u << ((k4.y & 1) * 16));
            atomicAdd(&h[k4.z >> 1], 1u << ((k4.z & 1) * 16));
            atomicAdd(&h[k4.w >> 1], 1u << ((k4.w & 1) * 16));
        } else {
            for (int j = i; j < se; ++j) {
                int k = keys[j];
                atomicAdd(&h[k >> 1], 1u << ((k & 1) * 16));
            }
        }
    }
    __syncthreads();
    unsigned int* __restrict__ outp = partial + (size_t)b * words;
    for (int w = tid; w < words; w += HIST_THREADS) outp[w] = h[w];
}

// ---------------- sum the 2*HB partial histograms -> cntS, cntD ----------------
__global__ void reduce_kernel(const unsigned int* __restrict__ partial,
                              int* __restrict__ cntS, int* __restrict__ cntD,
                              int N, int words) {
    int w = blockIdx.x * blockDim.x + threadIdx.x;
    if (w >= words) return;
    unsigned int dlo = 0, dhi = 0, slo = 0, shi = 0;
#pragma unroll
    for (int b = 0; b < HB; ++b) {
        unsigned int vd = partial[(size_t)b * words + w];
        unsigned int vs = partial[(size_t)(b + HB) * words + w];
        dlo += vd & 0xffffu; dhi += vd >> 16;
        slo += vs & 0xffffu; shi += vs >> 16;
    }
    int n0 = 2 * w, n1 = 2 * w + 1;
    cntD[n0] = (int)dlo; cntS[n0] = (int)slo;
    if (n1 < N) { cntD[n1] = (int)dhi; cntS[n1] = (int)shi; }
}

// ---------------- scan phase 1: per-block partial sums of cntD ----------------
__global__ void scan_partial(const int* __restrict__ cnt, int* __restrict__ blockSums, int N) {
    __shared__ int red[256];
    int base = blockIdx.x * CHUNK + (int)threadIdx.x * 4;
    int s = 0;
    if (base + 3 < N) {
        int4 v = *reinterpret_cast<const int4*>(cnt + base);
        s = v.x + v.y + v.z + v.w;
    } else {
        for (int i = 0; i < 4; ++i) { int idx = base + i; if (idx < N) s += cnt[idx]; }
    }
    red[threadIdx.x] = s;
    __syncthreads();
    for (int off = 128; off > 0; off >>= 1) {
        if ((int)threadIdx.x < off) red[threadIdx.x] += red[threadIdx.x + off];
        __syncthreads();
    }
    if (threadIdx.x == 0) blockSums[blockIdx.x] = red[0];
}

// ---------------- scan phase 2: one wave scans the block sums ----------------
__global__ void scan_sums(const int* __restrict__ bs, int* __restrict__ boff,
                          int NB, int* __restrict__ rowptr, int N) {
    int lane = threadIdx.x;
    int carry = 0;
    for (int base = 0; base < NB; base += 64) {
        int i = base + lane;
        int orig = (i < NB) ? bs[i] : 0;
        int v = orig;
        for (int off = 1; off < 64; off <<= 1) {
            int t = __shfl_up(v, off);
            if (lane >= off) v += t;
        }
        if (i < NB) boff[i] = carry + v - orig;
        carry += __shfl(v, 63);
    }
    if (lane == 0) rowptr[N] = carry;
}

// ---------------- scan phase 3: apply + fused norms + cursor init ----------------
__global__ void scan_apply(const int* __restrict__ cntD, const int* __restrict__ cntS,
                           const int* __restrict__ boff, int* __restrict__ rowptr,
                           int* __restrict__ cursor, float* __restrict__ normS,
                           float* __restrict__ normD, int N) {
    __shared__ int tsum[256];
    int tid = threadIdx.x;
    int base = blockIdx.x * CHUNK + tid * 4;
    int4 c = make_int4(0, 0, 0, 0);
    bool full = (base + 3 < N);
    if (full) {
        c = *reinterpret_cast<const int4*>(cntD + base);
    } else {
        if (base + 0 < N) c.x = cntD[base + 0];
        if (base + 1 < N) c.y = cntD[base + 1];
        if (base + 2 < N) c.z = cntD[base + 2];
        if (base + 3 < N) c.w = cntD[base + 3];
    }
    int s = c.x + c.y + c.z + c.w;
    tsum[tid] = s;
    __syncthreads();
    for (int off = 1; off < 256; off <<= 1) {
        int t = (tid >= off) ? tsum[tid - off] : 0;
        __syncthreads();
        tsum[tid] += t;
        __syncthreads();
    }
    int excl = tsum[tid] - s + boff[blockIdx.x];
    int r0 = excl, r1 = r0 + c.x, r2 = r1 + c.y, r3 = r2 + c.z;
    if (full) {
        *reinterpret_cast<int4*>(rowptr + base) = make_int4(r0, r1, r2, r3);
        *reinterpret_cast<int4*>(cursor + base) = make_int4(r0, r1, r2, r3);
        int4 cs = *reinterpret_cast<const int4*>(cntS + base);
        float4 nS = make_float4(rsqrtf(fmaxf((float)cs.x, 1.0f)), rsqrtf(fmaxf((float)cs.y, 1.0f)),
                                rsqrtf(fmaxf((float)cs.z, 1.0f)), rsqrtf(fmaxf((float)cs.w, 1.0f)));
        float4 nD = make_float4(rsqrtf(fmaxf((float)c.x, 1.0f)), rsqrtf(fmaxf((float)c.y, 1.0f)),
                                rsqrtf(fmaxf((float)c.z, 1.0f)), rsqrtf(fmaxf((float)c.w, 1.0f)));
        *reinterpret_cast<float4*>(normS + base) = nS;
        *reinterpret_cast<float4*>(normD + base) = nD;
    } else {
        int r[4] = {r0, r1, r2, r3};
        for (int i = 0; i < 4; ++i) {
            int idx = base + i;
            if (idx < N) {
                rowptr[idx] = r[i];
                cursor[idx] = r[i];
                normS[idx] = rsqrtf(fmaxf((float)cntS[idx], 1.0f));
                int cd = (i == 0) ? c.x : (i == 1) ? c.y : (i == 2) ? c.z : c.w;
                normD[idx] = rsqrtf(fmaxf((float)cd, 1.0f));
            }
        }
    }
}

// ---------------- CSR bucket fill (global cursor atomics, full-GPU parallel) ----------------
__global__ void fill_kernel(const int* __restrict__ src, const int* __restrict__ dst,
                            int* __restrict__ cursor, int* __restrict__ csr_src, int E) {
    int e = blockIdx.x * blockDim.x + threadIdx.x;
    if (e < E) {
        int d = dst[e];
        int pos = atomicAdd(&cursor[d], 1);
        csr_src[pos] = src[e];
    }
}

// ---------------- projection Y = X @ W ----------------
// 64 nodes/block; W (32KB) + padded X tile (33KB) in LDS; thread = 4 nodes x 4 cols;
// k-loop blocked by 4 so both x and w move through LDS as float4 (ds_read_b128).
__global__ __launch_bounds__(256)
void proj_kernel(const float* __restrict__ X, const float* __restrict__ W,
                 float* __restrict__ Y, int N) {
    __shared__ float w_s[IN_FEATS * OUT_FEATS];
    __shared__ float x_s[PROJ_NODES][IN_FEATS + XPAD];
    for (int i = threadIdx.x; i < IN_FEATS * OUT_FEATS / 4; i += 256)
        reinterpret_cast<float4*>(w_s)[i] = reinterpret_cast<const float4*>(W)[i];
    int base = blockIdx.x * PROJ_NODES;
    for (int i = threadIdx.x; i < PROJ_NODES * IN_FEATS / 4; i += 256) {
        int r = i >> 5;           // 32 float4 per row
        int c = (i & 31) * 4;
        int node = base + r;
        float4 v = (node < N) ? *reinterpret_cast<const float4*>(X + (size_t)node * IN_FEATS + c)
                              : make_float4(0.f, 0.f, 0.f, 0.f);
        *reinterpret_cast<float4*>(&x_s[r][c]) = v;
    }
    __syncthreads();
    int ns = (int)threadIdx.x >> 4;          // node-slot 0..15 -> rows ns*4..ns*4+3
    int jj = ((int)threadIdx.x & 15) * 4;    // col offset
    int r0 = ns * 4;
    float4 a0 = make_float4(0.f,0.f,0.f,0.f), a1 = a0, a2 = a0, a3 = a0;
    for (int k = 0; k < IN_FEATS; k += 4) {
        float4 x0 = *reinterpret_cast<const float4*>(&x_s[r0 + 0][k]);
        float4 x1 = *reinterpret_cast<const float4*>(&x_s[r0 + 1][k]);
        float4 x2 = *reinterpret_cast<const float4*>(&x_s[r0 + 2][k]);
        float4 x3 = *reinterpret_cast<const float4*>(&x_s[r0 + 3][k]);
#pragma unroll
        for (int q = 0; q < 4; ++q) {
            float4 w = *reinterpret_cast<const float4*>(&w_s[(k + q) * OUT_FEATS + jj]);
            float e0 = (q == 0) ? x0.x : (q == 1) ? x0.y : (q == 2) ? x0.z : x0.w;
            float e1 = (q == 0) ? x1.x : (q == 1) ? x1.y : (q == 2) ? x1.z : x1.w;
            float e2 = (q == 0) ? x2.x : (q == 1) ? x2.y : (q == 2) ? x2.z : x2.w;
            float e3 = (q == 0) ? x3.x : (q == 1) ? x3.y : (q == 2) ? x3.z : x3.w;
            a0.x = fmaf(e0, w.x, a0.x); a0.y = fmaf(e0, w.y, a0.y);
            a0.z = fmaf(e0, w.z, a0.z); a0.w = fmaf(e0, w.w, a0.w);
            a1.x = fmaf(e1, w.x, a1.x); a1.y = fmaf(e1, w.y, a1.y);
            a1.z = fmaf(e1, w.z, a1.z); a1.w = fmaf(e1, w.w, a1.w);
            a2.x = fmaf(e2, w.x, a2.x); a2.y = fmaf(e2, w.y, a2.y);
            a2.z = fmaf(e2, w.z, a2.z); a2.w = fmaf(e2, w.w, a2.w);
            a3.x = fmaf(e3, w.x, a3.x); a3.y = fmaf(e3, w.y, a3.y);
            a3.z = fmaf(e3, w.z, a3.z); a3.w = fmaf(e3, w.w, a3.w);
        }
    }
    float4 accs[4] = {a0, a1, a2, a3};
#pragma unroll
    for (int i = 0; i < 4; ++i) {
        int node = base + r0 + i;
        if (node < N)
            *reinterpret_cast<float4*>(&Y[(size_t)node * OUT_FEATS + jj]) = accs[i];
    }
}

// ---------------- gather hop ----------------
// one wave/node; 16 lanes x float4 = 64 feats; 4 edge-groups, 2x unrolled (8 loads in flight)
template <int EPI>
__global__ __launch_bounds__(256)
void gather_hop(const float* __restrict__ Yin, const int* __restrict__ rowptr,
                const int* __restrict__ csr_src, float* __restrict__ Yout,
                const float* __restrict__ vec, const float* __restrict__ bias,
                int N) {
    int node = blockIdx.x * 4 + ((int)threadIdx.x >> 6);
    int lane = (int)threadIdx.x & 63;
    int g = lane >> 4;
    int c = (lane & 15) * 4;
    if (node >= N) return;
    int beg = rowptr[node];
    int end = rowptr[node + 1];
    float4 acc = make_float4(0.f, 0.f, 0.f, 0.f);
    float4 acc2 = make_float4(0.f, 0.f, 0.f, 0.f);
    int k = beg + g;
    for (; k + 4 < end; k += 8) {
        int s0 = csr_src[k];
        int s1 = csr_src[k + 4];
        float4 v0 = *reinterpret_cast<const float4*>(Yin + (size_t)s0 * OUT_FEATS + c);
        float4 v1 = *reinterpret_cast<const float4*>(Yin + (size_t)s1 * OUT_FEATS + c);
        acc.x += v0.x; acc.y += v0.y; acc.z += v0.z; acc.w += v0.w;
        acc2.x += v1.x; acc2.y += v1.y; acc2.z += v1.z; acc2.w += v1.w;
    }
    if (k < end) {
        int s = csr_src[k];
        float4 v = *reinterpret_cast<const float4*>(Yin + (size_t)s * OUT_FEATS + c);
        acc.x += v.x; acc.y += v.y; acc.z += v.z; acc.w += v.w;
    }
    acc.x += acc2.x; acc.y += acc2.y; acc.z += acc2.z; acc.w += acc2.w;
    acc.x += __shfl_xor(acc.x, 16); acc.y += __shfl_xor(acc.y, 16);
    acc.z += __shfl_xor(acc.z, 16); acc.w += __shfl_xor(acc.w, 16);
    acc.x += __shfl_xor(acc.x, 32); acc.y += __shfl_xor(acc.y, 32);
    acc.z += __shfl_xor(acc.z, 32); acc.w += __shfl_xor(acc.w, 32);
    if (g == 0) {
        if (EPI == 1) {
            float sc = vec[node];
            acc.x *= sc; acc.y *= sc; acc.z *= sc; acc.w *= sc;
        }
        if (EPI == 2) {
            float sc = vec[node];
            float4 bb = *reinterpret_cast<const float4*>(bias + c);
            acc.x = fmaf(acc.x, sc, bb.x); acc.y = fmaf(acc.y, sc, bb.y);
            acc.z = fmaf(acc.z, sc, bb.z); acc.w = fmaf(acc.w, sc, bb.w);
        }
        *reinterpret_cast<float4*>(Yout + (size_t)node * OUT_FEATS + c) = acc;
    }
}

extern "C" void kernel_launch(void* const* d_in, const int* in_sizes, int n_in,
                              void* d_out, int out_size, void* d_ws, size_t ws_size,
                              hipStream_t stream) {
    const float* features = (const float*)d_in[0];
    const int*   src      = (const int*)d_in[1];
    const int*   dst      = (const int*)d_in[2];
    const float* weight   = (const float*)d_in[3];
    const float* bias     = (const float*)d_in[4];

    const int N = in_sizes[0] / IN_FEATS;   // 50000
    const int E = in_sizes[1];              // 640000
    const int NB = (N + CHUNK - 1) / CHUNK;
    const int words = (N + 1) / 2;
    const int slice = (((E + HB - 1) / HB) + 3) & ~3;

    char* p = (char*)d_ws;
    float* normS   = (float*)p;  p = align_up(p + sizeof(float) * N, 256);
    float* normD   = (float*)p;  p = align_up(p + sizeof(float) * N, 256);
    float* y0      = (float*)p;  p = align_up(p + sizeof(float) * (size_t)N * OUT_FEATS, 256);
    float* y1      = (float*)p;  p = align_up(p + sizeof(float) * (size_t)N * OUT_FEATS, 256);
    int*   cntS    = (int*)p;    p = align_up(p + sizeof(int) * N, 256);
    int*   cntD    = (int*)p;    p = align_up(p + sizeof(int) * N, 256);
    int*   rowptr  = (int*)p;    p = align_up(p + sizeof(int) * (N + 1), 256);
    int*   cursor  = (int*)p;    p = align_up(p + sizeof(int) * N, 256);
    int*   bsums   = (int*)p;    p = align_up(p + sizeof(int) * NB, 256);
    int*   boff    = (int*)p;    p = align_up(p + sizeof(int) * NB, 256);
    int*   csr_src = (int*)p;    p = align_up(p + sizeof(int) * (size_t)E, 256);

    // partial histograms (2*HB*words u32 = 6.4MB) alias y1: y1 first written by hop1,
    // after reduce_kernel's last read of the partials.
    unsigned int* partial = (unsigned int*)y1;

    float* out = (float*)d_out;

    // --- counts via LDS histograms (low write-through traffic), then scan ---
    hist_kernel<<<2 * HB, HIST_THREADS, 0, stream>>>(src, dst, partial, E, slice, words);
    reduce_kernel<<<(words + 255) / 256, 256, 0, stream>>>(partial, cntS, cntD, N, words);
    scan_partial<<<NB, 256, 0, stream>>>(cntD, bsums, N);
    scan_sums<<<1, 64, 0, stream>>>(bsums, boff, NB, rowptr, N);
    scan_apply<<<NB, 256, 0, stream>>>(cntD, cntS, boff, rowptr, cursor, normS, normD, N);
    // --- fill with global cursor atomics (full-GPU parallel) ---
    fill_kernel<<<(E + 255) / 256, 256, 0, stream>>>(src, dst, cursor, csr_src, E);

    // --- projection (A and W commute): y0 = X @ W ---
    proj_kernel<<<(N + PROJ_NODES - 1) / PROJ_NODES, 256, 0, stream>>>(features, weight, y0, N);

    const int hop_blocks = (N + 3) / 4;
    // hop 1: y1 = A y0
    gather_hop<0><<<hop_blocks, 256, 0, stream>>>(y0, rowptr, csr_src, y1, nullptr, nullptr, N);
    // hop 2: y0 = normS .* (A y1)
    gather_hop<1><<<hop_blocks, 256, 0, stream>>>(y1, rowptr, csr_src, y0, normS, nullptr, N);
    // hop 3: out = normD .* (A y0) + bias
    gather_hop<2><<<hop_blocks, 256, 0, stream>>>(y0, rowptr, csr_src, out, normD, bias, N);
}

// Round 6
// 149.541 us; speedup vs baseline: 1.8700x; 1.0250x over previous
//
#include <hip/hip_runtime.h>
#include <hip/hip_bf16.h>

#define IN_FEATS 128
#define OUT_FEATS 64
#define CHUNK 1024        // nodes per scan/prefix chunk
#define PB 512            // prefix_kernel threads (PB words = CHUNK nodes)
#define HB 32             // histogram/fill blocks per key array
#define HIST_THREADS 1024
#define MAX_WORDS 25000   // (N+1)/2 for N=50000 -> 100KB LDS packed u16 histogram
#define PROJ_NODES 64
#define XPAD 4

static inline char* align_up(char* p, size_t a) {
    return (char*)(((uintptr_t)p + a - 1) & ~(uintptr_t)(a - 1));
}

// ---- bf16 helpers (RNE pack, shift unpack; math always fp32) ----
__device__ __forceinline__ unsigned pack_bf16(float a, float b) {
    unsigned ua = __float_as_uint(a), ub = __float_as_uint(b);
    ua = (ua + 0x7fffu + ((ua >> 16) & 1u)) >> 16;
    ub = (ub + 0x7fffu + ((ub >> 16) & 1u)) >> 16;
    return ua | (ub << 16);
}
__device__ __forceinline__ float bf16_lo(unsigned u) { return __uint_as_float(u << 16); }
__device__ __forceinline__ float bf16_hi(unsigned u) { return __uint_as_float(u & 0xffff0000u); }

// ---------------- per-block LDS histogram (packed u16 pairs) ----------------
// blocks 0..HB-1: dst slices; blocks HB..2HB-1: src slices
__global__ __launch_bounds__(HIST_THREADS)
void hist_kernel(const int* __restrict__ src, const int* __restrict__ dst,
                 unsigned int* __restrict__ partial, int E, int slice, int words) {
    __shared__ unsigned int h[MAX_WORDS];
    int tid = threadIdx.x;
    for (int w = tid; w < words; w += HIST_THREADS) h[w] = 0u;
    __syncthreads();
    int b = blockIdx.x;
    const int* __restrict__ keys = (b < HB) ? dst : src;
    int sb = (b & (HB - 1)) * slice;
    int se = min(sb + slice, E);
    for (int i = sb + tid * 4; i < se; i += HIST_THREADS * 4) {
        if (i + 3 < se) {
            int4 k4 = *reinterpret_cast<const int4*>(keys + i);
            atomicAdd(&h[k4.x >> 1], 1u << ((k4.x & 1) * 16));
            atomicAdd(&h[k4.y >> 1], 1u << ((k4.y & 1) * 16));
            atomicAdd(&h[k4.z >> 1], 1u << ((k4.z & 1) * 16));
            atomicAdd(&h[k4.w >> 1], 1u << ((k4.w & 1) * 16));
        } else {
            for (int j = i; j < se; ++j) {
                int k = keys[j];
                atomicAdd(&h[k >> 1], 1u << ((k & 1) * 16));
            }
        }
    }
    __syncthreads();
    unsigned int* __restrict__ outp = partial + (size_t)b * words;
    for (int w = tid; w < words; w += HIST_THREADS) outp[w] = h[w];
}

// ---------------- prefix over blocks + counts + scan-chunk partial sums ----------------
// thread w: exclusive prefix of dst-partials across HB blocks (packed u16, per-node
// totals < 65536 so no cross-half carry), final sums -> cntD/cntS; block covers
// PB words = CHUNK nodes and emits its cntD chunk-sum into bsums (fuses scan_partial).
__global__ __launch_bounds__(PB)
void prefix_kernel(const unsigned int* __restrict__ partial, unsigned int* __restrict__ pprefix,
                   int* __restrict__ cntS, int* __restrict__ cntD, int* __restrict__ bsums,
                   int N, int words) {
    __shared__ int red[PB];
    int tid = threadIdx.x;
    int w = blockIdx.x * PB + tid;
    int dtot = 0;
    if (w < words) {
        unsigned run = 0;
#pragma unroll
        for (int b = 0; b < HB; ++b) {
            unsigned v = partial[(size_t)b * words + w];
            pprefix[(size_t)b * words + w] = run;
            run += v;
        }
        unsigned s = 0;
#pragma unroll
        for (int b = 0; b < HB; ++b) s += partial[(size_t)(b + HB) * words + w];
        int n0 = 2 * w, n1 = 2 * w + 1;
        int dlo = (int)(run & 0xffffu), dhi = (int)(run >> 16);
        cntD[n0] = dlo; cntS[n0] = (int)(s & 0xffffu);
        dtot = dlo;
        if (n1 < N) { cntD[n1] = dhi; cntS[n1] = (int)(s >> 16); dtot += dhi; }
    }
    red[tid] = dtot;
    __syncthreads();
    for (int off = PB / 2; off > 0; off >>= 1) {
        if (tid < off) red[tid] += red[tid + off];
        __syncthreads();
    }
    if (tid == 0) bsums[blockIdx.x] = red[0];
}

// ---------------- scan phase 2: one wave scans the chunk sums ----------------
__global__ void scan_sums(const int* __restrict__ bs, int* __restrict__ boff,
                          int NB, int* __restrict__ rowptr, int N) {
    int lane = threadIdx.x;
    int carry = 0;
    for (int base = 0; base < NB; base += 64) {
        int i = base + lane;
        int orig = (i < NB) ? bs[i] : 0;
        int v = orig;
        for (int off = 1; off < 64; off <<= 1) {
            int t = __shfl_up(v, off);
            if (lane >= off) v += t;
        }
        if (i < NB) boff[i] = carry + v - orig;
        carry += __shfl(v, 63);
    }
    if (lane == 0) rowptr[N] = carry;
}

// ---------------- scan phase 3: apply + fused norms ----------------
__global__ void scan_apply(const int* __restrict__ cntD, const int* __restrict__ cntS,
                           const int* __restrict__ boff, int* __restrict__ rowptr,
                           float* __restrict__ normS, float* __restrict__ normD, int N) {
    __shared__ int tsum[256];
    int tid = threadIdx.x;
    int base = blockIdx.x * CHUNK + tid * 4;
    int4 c = make_int4(0, 0, 0, 0);
    bool full = (base + 3 < N);
    if (full) {
        c = *reinterpret_cast<const int4*>(cntD + base);
    } else {
        if (base + 0 < N) c.x = cntD[base + 0];
        if (base + 1 < N) c.y = cntD[base + 1];
        if (base + 2 < N) c.z = cntD[base + 2];
        if (base + 3 < N) c.w = cntD[base + 3];
    }
    int s = c.x + c.y + c.z + c.w;
    tsum[tid] = s;
    __syncthreads();
    for (int off = 1; off < 256; off <<= 1) {
        int t = (tid >= off) ? tsum[tid - off] : 0;
        __syncthreads();
        tsum[tid] += t;
        __syncthreads();
    }
    int excl = tsum[tid] - s + boff[blockIdx.x];
    int r0 = excl, r1 = r0 + c.x, r2 = r1 + c.y, r3 = r2 + c.z;
    if (full) {
        *reinterpret_cast<int4*>(rowptr + base) = make_int4(r0, r1, r2, r3);
        int4 cs = *reinterpret_cast<const int4*>(cntS + base);
        float4 nS = make_float4(rsqrtf(fmaxf((float)cs.x, 1.0f)), rsqrtf(fmaxf((float)cs.y, 1.0f)),
                                rsqrtf(fmaxf((float)cs.z, 1.0f)), rsqrtf(fmaxf((float)cs.w, 1.0f)));
        float4 nD = make_float4(rsqrtf(fmaxf((float)c.x, 1.0f)), rsqrtf(fmaxf((float)c.y, 1.0f)),
                                rsqrtf(fmaxf((float)c.z, 1.0f)), rsqrtf(fmaxf((float)c.w, 1.0f)));
        *reinterpret_cast<float4*>(normS + base) = nS;
        *reinterpret_cast<float4*>(normD + base) = nD;
    } else {
        int r[4] = {r0, r1, r2, r3};
        for (int i = 0; i < 4; ++i) {
            int idx = base + i;
            if (idx < N) {
                rowptr[idx] = r[i];
                normS[idx] = rsqrtf(fmaxf((float)cntS[idx], 1.0f));
                int cd = (i == 0) ? c.x : (i == 1) ? c.y : (i == 2) ? c.z : c.w;
                normD[idx] = rsqrtf(fmaxf((float)cd, 1.0f));
            }
        }
    }
}

// ---------------- CSR fill: LDS cursors seeded from precomputed prefixes ----------------
// block b: cur = pprefix[b] (packed u16), pos = rowptr[bin] + local offset -> globally
// disjoint positions, zero global atomics.
__global__ __launch_bounds__(HIST_THREADS)
void fill_kernel(const int* __restrict__ src, const int* __restrict__ dst,
                 const unsigned int* __restrict__ pprefix, const int* __restrict__ rowptr,
                 int* __restrict__ csr_src, int E, int slice, int words) {
    __shared__ unsigned int cur[MAX_WORDS];
    int tid = threadIdx.x;
    int b = blockIdx.x;
    const unsigned int* __restrict__ pp = pprefix + (size_t)b * words;
    for (int w = tid; w < words; w += HIST_THREADS) cur[w] = pp[w];
    __syncthreads();
    int sb = b * slice;
    int se = min(sb + slice, E);
    for (int i = sb + tid * 4; i < se; i += HIST_THREADS * 4) {
        if (i + 3 < se) {
            int4 d4 = *reinterpret_cast<const int4*>(dst + i);
            int4 s4 = *reinterpret_cast<const int4*>(src + i);
            int dd[4] = {d4.x, d4.y, d4.z, d4.w};
            int ss[4] = {s4.x, s4.y, s4.z, s4.w};
#pragma unroll
            for (int j = 0; j < 4; ++j) {
                int bin = dd[j];
                unsigned int sh = (unsigned)(bin & 1) * 16u;
                unsigned int old = atomicAdd(&cur[bin >> 1], 1u << sh);
                int off = (int)((old >> sh) & 0xffffu);
                csr_src[rowptr[bin] + off] = ss[j];
            }
        } else {
            for (int j = i; j < se; ++j) {
                int bin = dst[j];
                unsigned int sh = (unsigned)(bin & 1) * 16u;
                unsigned int old = atomicAdd(&cur[bin >> 1], 1u << sh);
                int off = (int)((old >> sh) & 0xffffu);
                csr_src[rowptr[bin] + off] = src[j];
            }
        }
    }
}

// ---------------- projection Y(bf16) = X(f32) @ W ----------------
__global__ __launch_bounds__(256)
void proj_kernel(const float* __restrict__ X, const float* __restrict__ W,
                 uint2* __restrict__ Y, int N) {
    __shared__ float w_s[IN_FEATS * OUT_FEATS];
    __shared__ float x_s[PROJ_NODES][IN_FEATS + XPAD];
    for (int i = threadIdx.x; i < IN_FEATS * OUT_FEATS / 4; i += 256)
        reinterpret_cast<float4*>(w_s)[i] = reinterpret_cast<const float4*>(W)[i];
    int base = blockIdx.x * PROJ_NODES;
    for (int i = threadIdx.x; i < PROJ_NODES * IN_FEATS / 4; i += 256) {
        int r = i >> 5;
        int c = (i & 31) * 4;
        int node = base + r;
        float4 v = (node < N) ? *reinterpret_cast<const float4*>(X + (size_t)node * IN_FEATS + c)
                              : make_float4(0.f, 0.f, 0.f, 0.f);
        *reinterpret_cast<float4*>(&x_s[r][c]) = v;
    }
    __syncthreads();
    int ns = (int)threadIdx.x >> 4;
    int jj = ((int)threadIdx.x & 15) * 4;
    int r0 = ns * 4;
    float4 a0 = make_float4(0.f,0.f,0.f,0.f), a1 = a0, a2 = a0, a3 = a0;
    for (int k = 0; k < IN_FEATS; k += 4) {
        float4 x0 = *reinterpret_cast<const float4*>(&x_s[r0 + 0][k]);
        float4 x1 = *reinterpret_cast<const float4*>(&x_s[r0 + 1][k]);
        float4 x2 = *reinterpret_cast<const float4*>(&x_s[r0 + 2][k]);
        float4 x3 = *reinterpret_cast<const float4*>(&x_s[r0 + 3][k]);
#pragma unroll
        for (int q = 0; q < 4; ++q) {
            float4 w = *reinterpret_cast<const float4*>(&w_s[(k + q) * OUT_FEATS + jj]);
            float e0 = (q == 0) ? x0.x : (q == 1) ? x0.y : (q == 2) ? x0.z : x0.w;
            float e1 = (q == 0) ? x1.x : (q == 1) ? x1.y : (q == 2) ? x1.z : x1.w;
            float e2 = (q == 0) ? x2.x : (q == 1) ? x2.y : (q == 2) ? x2.z : x2.w;
            float e3 = (q == 0) ? x3.x : (q == 1) ? x3.y : (q == 2) ? x3.z : x3.w;
            a0.x = fmaf(e0, w.x, a0.x); a0.y = fmaf(e0, w.y, a0.y);
            a0.z = fmaf(e0, w.z, a0.z); a0.w = fmaf(e0, w.w, a0.w);
            a1.x = fmaf(e1, w.x, a1.x); a1.y = fmaf(e1, w.y, a1.y);
            a1.z = fmaf(e1, w.z, a1.z); a1.w = fmaf(e1, w.w, a1.w);
            a2.x = fmaf(e2, w.x, a2.x); a2.y = fmaf(e2, w.y, a2.y);
            a2.z = fmaf(e2, w.z, a2.z); a2.w = fmaf(e2, w.w, a2.w);
            a3.x = fmaf(e3, w.x, a3.x); a3.y = fmaf(e3, w.y, a3.y);
            a3.z = fmaf(e3, w.z, a3.z); a3.w = fmaf(e3, w.w, a3.w);
        }
    }
    float4 accs[4] = {a0, a1, a2, a3};
#pragma unroll
    for (int i = 0; i < 4; ++i) {
        int node = base + r0 + i;
        if (node < N) {
            uint2 o;
            o.x = pack_bf16(accs[i].x, accs[i].y);
            o.y = pack_bf16(accs[i].z, accs[i].w);
            Y[(size_t)node * (OUT_FEATS / 4) + (jj >> 2)] = o;
        }
    }
}

// ---------------- gather hop over bf16 rows ----------------
// one wave/node; 16 lanes x uint2 (4 bf16) cover 64 feats; 4 edge-groups, 2x unroll.
// EPI: 0 -> bf16 out; 1 -> *vec[node], bf16 out; 2 -> *vec[node]+bias, f32 out
template <int EPI>
__global__ __launch_bounds__(256)
void gather_hop(const uint2* __restrict__ Yin, const int* __restrict__ rowptr,
                const int* __restrict__ csr_src, void* __restrict__ Yout,
                const float* __restrict__ vec, const float* __restrict__ bias,
                int N) {
    int node = blockIdx.x * 4 + ((int)threadIdx.x >> 6);
    int lane = (int)threadIdx.x & 63;
    int g = lane >> 4;
    int ci = lane & 15;   // uint2 index within row; feats 4*ci..4*ci+3
    if (node >= N) return;
    int beg = rowptr[node];
    int end = rowptr[node + 1];
    float4 acc = make_float4(0.f, 0.f, 0.f, 0.f);
    float4 acc2 = make_float4(0.f, 0.f, 0.f, 0.f);
    int k = beg + g;
    for (; k + 4 < end; k += 8) {
        int s0 = csr_src[k];
        int s1 = csr_src[k + 4];
        uint2 v0 = Yin[(size_t)s0 * (OUT_FEATS / 4) + ci];
        uint2 v1 = Yin[(size_t)s1 * (OUT_FEATS / 4) + ci];
        acc.x += bf16_lo(v0.x); acc.y += bf16_hi(v0.x);
        acc.z += bf16_lo(v0.y); acc.w += bf16_hi(v0.y);
        acc2.x += bf16_lo(v1.x); acc2.y += bf16_hi(v1.x);
        acc2.z += bf16_lo(v1.y); acc2.w += bf16_hi(v1.y);
    }
    if (k < end) {
        uint2 v = Yin[(size_t)csr_src[k] * (OUT_FEATS / 4) + ci];
        acc.x += bf16_lo(v.x); acc.y += bf16_hi(v.x);
        acc.z += bf16_lo(v.y); acc.w += bf16_hi(v.y);
    }
    acc.x += acc2.x; acc.y += acc2.y; acc.z += acc2.z; acc.w += acc2.w;
    acc.x += __shfl_xor(acc.x, 16); acc.y += __shfl_xor(acc.y, 16);
    acc.z += __shfl_xor(acc.z, 16); acc.w += __shfl_xor(acc.w, 16);
    acc.x += __shfl_xor(acc.x, 32); acc.y += __shfl_xor(acc.y, 32);
    acc.z += __shfl_xor(acc.z, 32); acc.w += __shfl_xor(acc.w, 32);
    if (g == 0) {
        if (EPI == 1) {
            float sc = vec[node];
            acc.x *= sc; acc.y *= sc; acc.z *= sc; acc.w *= sc;
        }
        if (EPI == 2) {
            float sc = vec[node];
            float4 bb = *reinterpret_cast<const float4*>(bias + ci * 4);
            acc.x = fmaf(acc.x, sc, bb.x); acc.y = fmaf(acc.y, sc, bb.y);
            acc.z = fmaf(acc.z, sc, bb.z); acc.w = fmaf(acc.w, sc, bb.w);
            reinterpret_cast<float4*>(Yout)[(size_t)node * (OUT_FEATS / 4) + ci] = acc;
        } else {
            uint2 o;
            o.x = pack_bf16(acc.x, acc.y);
            o.y = pack_bf16(acc.z, acc.w);
            reinterpret_cast<uint2*>(Yout)[(size_t)node * (OUT_FEATS / 4) + ci] = o;
        }
    }
}

extern "C" void kernel_launch(void* const* d_in, const int* in_sizes, int n_in,
                              void* d_out, int out_size, void* d_ws, size_t ws_size,
                              hipStream_t stream) {
    const float* features = (const float*)d_in[0];
    const int*   src      = (const int*)d_in[1];
    const int*   dst      = (const int*)d_in[2];
    const float* weight   = (const float*)d_in[3];
    const float* bias     = (const float*)d_in[4];

    const int N = in_sizes[0] / IN_FEATS;   // 50000
    const int E = in_sizes[1];              // 640000
    const int words = (N + 1) / 2;          // 25000
    const int NB = (words + PB - 1) / PB;   // prefix blocks == scan chunks (49)
    const int slice = (((E + HB - 1) / HB) + 3) & ~3;

    char* p = (char*)d_ws;
    float* normS   = (float*)p;  p = align_up(p + sizeof(float) * N, 256);
    float* normD   = (float*)p;  p = align_up(p + sizeof(float) * N, 256);
    uint2* y0      = (uint2*)p;  p = align_up(p + sizeof(uint2) * (size_t)N * (OUT_FEATS / 4), 256);
    uint2* y1      = (uint2*)p;  p = align_up(p + sizeof(uint2) * (size_t)N * (OUT_FEATS / 4), 256);
    int*   cntS    = (int*)p;    p = align_up(p + sizeof(int) * N, 256);
    int*   cntD    = (int*)p;    p = align_up(p + sizeof(int) * N, 256);
    int*   rowptr  = (int*)p;    p = align_up(p + sizeof(int) * (N + 1), 256);
    int*   bsums   = (int*)p;    p = align_up(p + sizeof(int) * NB, 256);
    int*   boff    = (int*)p;    p = align_up(p + sizeof(int) * NB, 256);
    int*   csr_src = (int*)p;    p = align_up(p + sizeof(int) * (size_t)E, 256);
    unsigned int* partial = (unsigned int*)p;  p = align_up(p + sizeof(unsigned) * (size_t)(2 * HB) * words, 256);
    unsigned int* pprefix = (unsigned int*)p;  p = align_up(p + sizeof(unsigned) * (size_t)HB * words, 256);

    float* out = (float*)d_out;

    // --- CSR build + norms: LDS histograms -> parallel prefix -> scan -> LDS-cursor fill ---
    hist_kernel<<<2 * HB, HIST_THREADS, 0, stream>>>(src, dst, partial, E, slice, words);
    prefix_kernel<<<NB, PB, 0, stream>>>(partial, pprefix, cntS, cntD, bsums, N, words);
    scan_sums<<<1, 64, 0, stream>>>(bsums, boff, NB, rowptr, N);
    scan_apply<<<NB, 256, 0, stream>>>(cntD, cntS, boff, rowptr, normS, normD, N);
    fill_kernel<<<HB, HIST_THREADS, 0, stream>>>(src, dst, pprefix, rowptr, csr_src, E, slice, words);

    // --- projection (A and W commute): y0 = bf16(X @ W) ---
    proj_kernel<<<(N + PROJ_NODES - 1) / PROJ_NODES, 256, 0, stream>>>(features, weight, y0, N);

    const int hop_blocks = (N + 3) / 4;
    // hop 1: y1 = A y0                    (bf16 -> bf16)
    gather_hop<0><<<hop_blocks, 256, 0, stream>>>(y0, rowptr, csr_src, (void*)y1, nullptr, nullptr, N);
    // hop 2: y0 = normS .* (A y1)         (bf16 -> bf16)
    gather_hop<1><<<hop_blocks, 256, 0, stream>>>(y1, rowptr, csr_src, (void*)y0, normS, nullptr, N);
    // hop 3: out = normD .* (A y0) + bias (bf16 -> f32)
    gather_hop<2><<<hop_blocks, 256, 0, stream>>>(y0, rowptr, csr_src, (void*)out, normD, bias, N);
}

// Round 7
// 136.133 us; speedup vs baseline: 2.0541x; 1.0985x over previous
//
#include <hip/hip_runtime.h>
#include <hip/hip_bf16.h>

#define IN_FEATS 128
#define OUT_FEATS 64
#define HB_D 128          // dst histogram/fill slices
#define HB_S 64           // src histogram slices
#define PB 512            // prefix_kernel threads (PB words = 1024 nodes per chunk)
#define MAX_WORDS 25000   // (N+1)/2 for N=50000 (packed u16 histogram, 100KB)
#define SMEM_WORDS 25088  // K1 shared: max(hist 25000, proj 8192 W + 128*132 X)
#define PROJ_NODES 128
#define XPAD 4

static inline char* align_up(char* p, size_t a) {
    return (char*)(((uintptr_t)p + a - 1) & ~(uintptr_t)(a - 1));
}

// ---- bf16 helpers (RNE pack, shift unpack; math always fp32) ----
__device__ __forceinline__ unsigned pack_bf16(float a, float b) {
    unsigned ua = __float_as_uint(a), ub = __float_as_uint(b);
    ua = (ua + 0x7fffu + ((ua >> 16) & 1u)) >> 16;
    ub = (ub + 0x7fffu + ((ub >> 16) & 1u)) >> 16;
    return ua | (ub << 16);
}
__device__ __forceinline__ float bf16_lo(unsigned u) { return __uint_as_float(u << 16); }
__device__ __forceinline__ float bf16_hi(unsigned u) { return __uint_as_float(u & 0xffff0000u); }

// ================= K1: fused histogram (192 blocks) + projection (391 blocks) ==========
// blocks [0, HB_D)            : packed-u16 LDS histogram of dst slice b
// blocks [HB_D, HB_D+HB_S)    : packed-u16 LDS histogram of src slice b-HB_D
// blocks [HB_D+HB_S, ...)     : proj: y0 = bf16(X @ W), 128 nodes per block
__global__ __launch_bounds__(1024)
void hist_proj_kernel(const int* __restrict__ src, const int* __restrict__ dst,
                      const float* __restrict__ X, const float* __restrict__ W,
                      unsigned* __restrict__ partial, uint2* __restrict__ Y,
                      int N, int E, int slice_d, int slice_s, int words) {
    __shared__ unsigned smem[SMEM_WORDS];
    int tid = (int)threadIdx.x;
    int b = (int)blockIdx.x;

    if (b < HB_D + HB_S) {
        // ---------------- histogram path ----------------
        unsigned* h = smem;
        for (int w = tid; w < words; w += 1024) h[w] = 0u;
        __syncthreads();
        const int* __restrict__ keys;
        int sb, se;
        if (b < HB_D) { keys = dst; sb = b * slice_d; se = min(sb + slice_d, E); }
        else          { keys = src; sb = (b - HB_D) * slice_s; se = min(sb + slice_s, E); }
        for (int i = sb + tid * 4; i < se; i += 1024 * 4) {
            if (i + 3 < se) {
                int4 k4 = *reinterpret_cast<const int4*>(keys + i);
                atomicAdd(&h[k4.x >> 1], 1u << ((k4.x & 1) * 16));
                atomicAdd(&h[k4.y >> 1], 1u << ((k4.y & 1) * 16));
                atomicAdd(&h[k4.z >> 1], 1u << ((k4.z & 1) * 16));
                atomicAdd(&h[k4.w >> 1], 1u << ((k4.w & 1) * 16));
            } else {
                for (int j = i; j < se; ++j) {
                    int k = keys[j];
                    atomicAdd(&h[k >> 1], 1u << ((k & 1) * 16));
                }
            }
        }
        __syncthreads();
        unsigned* __restrict__ outp = partial + (size_t)b * words;
        for (int w = tid; w < words; w += 1024) outp[w] = h[w];
    } else {
        // ---------------- projection path ----------------
        float* w_s = (float*)smem;                                     // 8192 floats
        float (*x_s)[IN_FEATS + XPAD] = (float (*)[IN_FEATS + XPAD])(w_s + IN_FEATS * OUT_FEATS);
        for (int i = tid; i < IN_FEATS * OUT_FEATS / 4; i += 1024)
            reinterpret_cast<float4*>(w_s)[i] = reinterpret_cast<const float4*>(W)[i];
        int base = (b - (HB_D + HB_S)) * PROJ_NODES;
        for (int i = tid; i < PROJ_NODES * IN_FEATS / 4; i += 1024) {
            int r = i >> 5;            // 32 float4 per row
            int c = (i & 31) * 4;
            int node = base + r;
            float4 v = (node < N) ? *reinterpret_cast<const float4*>(X + (size_t)node * IN_FEATS + c)
                                  : make_float4(0.f, 0.f, 0.f, 0.f);
            *reinterpret_cast<float4*>(&x_s[r][c]) = v;
        }
        __syncthreads();
        int slot = tid >> 4;                 // 64 slots -> node pair (2*slot, 2*slot+1)
        int jj = (tid & 15) * 4;             // col base (4 cols)
        int r0 = slot * 2, r1 = r0 + 1;
        float4 a0 = make_float4(0.f, 0.f, 0.f, 0.f), a1 = a0;
        for (int k = 0; k < IN_FEATS; k += 4) {
            float4 x0 = *reinterpret_cast<const float4*>(&x_s[r0][k]);
            float4 x1 = *reinterpret_cast<const float4*>(&x_s[r1][k]);
#pragma unroll
            for (int q = 0; q < 4; ++q) {
                float4 w = *reinterpret_cast<const float4*>(&w_s[(k + q) * OUT_FEATS + jj]);
                float e0 = (q == 0) ? x0.x : (q == 1) ? x0.y : (q == 2) ? x0.z : x0.w;
                float e1 = (q == 0) ? x1.x : (q == 1) ? x1.y : (q == 2) ? x1.z : x1.w;
                a0.x = fmaf(e0, w.x, a0.x); a0.y = fmaf(e0, w.y, a0.y);
                a0.z = fmaf(e0, w.z, a0.z); a0.w = fmaf(e0, w.w, a0.w);
                a1.x = fmaf(e1, w.x, a1.x); a1.y = fmaf(e1, w.y, a1.y);
                a1.z = fmaf(e1, w.z, a1.z); a1.w = fmaf(e1, w.w, a1.w);
            }
        }
        int n0 = base + r0, n1 = base + r1;
        if (n0 < N) {
            uint2 o; o.x = pack_bf16(a0.x, a0.y); o.y = pack_bf16(a0.z, a0.w);
            Y[(size_t)n0 * (OUT_FEATS / 4) + (jj >> 2)] = o;
        }
        if (n1 < N) {
            uint2 o; o.x = pack_bf16(a1.x, a1.y); o.y = pack_bf16(a1.z, a1.w);
            Y[(size_t)n1 * (OUT_FEATS / 4) + (jj >> 2)] = o;
        }
    }
}

// ========== K2: per-word exclusive prefix across dst blocks + counts + chunk sums ======
__global__ __launch_bounds__(PB)
void prefix_kernel(const unsigned* __restrict__ partial, unsigned* __restrict__ pprefix,
                   int* __restrict__ cntS, int* __restrict__ cntD, int* __restrict__ bsums,
                   int N, int words) {
    __shared__ int red[PB];
    int tid = (int)threadIdx.x;
    int w = (int)blockIdx.x * PB + tid;
    int dtot = 0;
    if (w < words) {
        unsigned run = 0;
#pragma unroll 8
        for (int b = 0; b < HB_D; ++b) {
            unsigned v = partial[(size_t)b * words + w];
            pprefix[(size_t)b * words + w] = run;
            run += v;
        }
        unsigned s = 0;
#pragma unroll 8
        for (int b = HB_D; b < HB_D + HB_S; ++b) s += partial[(size_t)b * words + w];
        int dlo = (int)(run & 0xffffu), dhi = (int)(run >> 16);
        int n1 = 2 * w + 1;
        if (n1 < N) {
            reinterpret_cast<int2*>(cntD)[w] = make_int2(dlo, dhi);
            reinterpret_cast<int2*>(cntS)[w] = make_int2((int)(s & 0xffffu), (int)(s >> 16));
            dtot = dlo + dhi;
        } else {
            cntD[2 * w] = dlo; cntS[2 * w] = (int)(s & 0xffffu);
            dtot = dlo;
        }
    }
    red[tid] = dtot;
    __syncthreads();
    for (int off = PB / 2; off > 0; off >>= 1) {
        if (tid < off) red[tid] += red[tid + off];
        __syncthreads();
    }
    if (tid == 0) bsums[blockIdx.x] = red[0];
}

// ========== K3: rowptr + norms; wave0 re-scans the (<=64) chunk sums inline ============
__global__ __launch_bounds__(256)
void scan_apply(const int* __restrict__ cntD, const int* __restrict__ cntS,
                const int* __restrict__ bsums, int* __restrict__ rowptr,
                float* __restrict__ normS, float* __restrict__ normD, int N, int NB) {
    __shared__ int tsum[256];
    __shared__ int sboff;
    int tid = (int)threadIdx.x;
    if (tid < 64) {                       // NB <= 64 by construction for this problem
        int v = (tid < NB) ? bsums[tid] : 0;
        int orig = v;
        for (int off = 1; off < 64; off <<= 1) {
            int t = __shfl_up(v, off);
            if (tid >= off) v += t;
        }
        if (tid == (int)blockIdx.x) sboff = v - orig;          // exclusive for this chunk
        if (blockIdx.x == 0 && tid == NB - 1) rowptr[N] = v;   // grand total
    }
    __syncthreads();
    int base = (int)blockIdx.x * 1024 + tid * 4;
    int4 c = make_int4(0, 0, 0, 0);
    bool full = (base + 3 < N);
    if (full) {
        c = *reinterpret_cast<const int4*>(cntD + base);
    } else {
        if (base + 0 < N) c.x = cntD[base + 0];
        if (base + 1 < N) c.y = cntD[base + 1];
        if (base + 2 < N) c.z = cntD[base + 2];
        if (base + 3 < N) c.w = cntD[base + 3];
    }
    int s = c.x + c.y + c.z + c.w;
    tsum[tid] = s;
    __syncthreads();
    for (int off = 1; off < 256; off <<= 1) {
        int t = (tid >= off) ? tsum[tid - off] : 0;
        __syncthreads();
        tsum[tid] += t;
        __syncthreads();
    }
    int excl = tsum[tid] - s + sboff;
    int r0 = excl, r1 = r0 + c.x, r2 = r1 + c.y, r3 = r2 + c.z;
    if (full) {
        *reinterpret_cast<int4*>(rowptr + base) = make_int4(r0, r1, r2, r3);
        int4 cs = *reinterpret_cast<const int4*>(cntS + base);
        float4 nS = make_float4(rsqrtf(fmaxf((float)cs.x, 1.0f)), rsqrtf(fmaxf((float)cs.y, 1.0f)),
                                rsqrtf(fmaxf((float)cs.z, 1.0f)), rsqrtf(fmaxf((float)cs.w, 1.0f)));
        float4 nD = make_float4(rsqrtf(fmaxf((float)c.x, 1.0f)), rsqrtf(fmaxf((float)c.y, 1.0f)),
                                rsqrtf(fmaxf((float)c.z, 1.0f)), rsqrtf(fmaxf((float)c.w, 1.0f)));
        *reinterpret_cast<float4*>(normS + base) = nS;
        *reinterpret_cast<float4*>(normD + base) = nD;
    } else {
        int r[4] = {r0, r1, r2, r3};
        for (int i = 0; i < 4; ++i) {
            int idx = base + i;
            if (idx < N) {
                rowptr[idx] = r[i];
                normS[idx] = rsqrtf(fmaxf((float)cntS[idx], 1.0f));
                int cd = (i == 0) ? c.x : (i == 1) ? c.y : (i == 2) ? c.z : c.w;
                normD[idx] = rsqrtf(fmaxf((float)cd, 1.0f));
            }
        }
    }
}

// ========== K4: CSR fill, LDS cursors seeded from precomputed per-block prefixes =======
__global__ __launch_bounds__(1024)
void fill_kernel(const int* __restrict__ src, const int* __restrict__ dst,
                 const unsigned* __restrict__ pprefix, const int* __restrict__ rowptr,
                 int* __restrict__ csr_src, int E, int slice, int words) {
    __shared__ unsigned cur[MAX_WORDS];
    int tid = (int)threadIdx.x;
    int b = (int)blockIdx.x;
    const unsigned* __restrict__ pp = pprefix + (size_t)b * words;
    for (int w = tid; w < words; w += 1024) cur[w] = pp[w];
    __syncthreads();
    int sb = b * slice;
    int se = min(sb + slice, E);
    for (int i = sb + tid * 4; i < se; i += 1024 * 4) {
        if (i + 3 < se) {
            int4 d4 = *reinterpret_cast<const int4*>(dst + i);
            int4 s4 = *reinterpret_cast<const int4*>(src + i);
            int dd[4] = {d4.x, d4.y, d4.z, d4.w};
            int ss[4] = {s4.x, s4.y, s4.z, s4.w};
#pragma unroll
            for (int j = 0; j < 4; ++j) {
                int bin = dd[j];
                unsigned sh = (unsigned)(bin & 1) * 16u;
                unsigned old = atomicAdd(&cur[bin >> 1], 1u << sh);
                int off = (int)((old >> sh) & 0xffffu);
                csr_src[rowptr[bin] + off] = ss[j];
            }
        } else {
            for (int j = i; j < se; ++j) {
                int bin = dst[j];
                unsigned sh = (unsigned)(bin & 1) * 16u;
                unsigned old = atomicAdd(&cur[bin >> 1], 1u << sh);
                int off = (int)((old >> sh) & 0xffffu);
                csr_src[rowptr[bin] + off] = src[j];
            }
        }
    }
}

// ================= gather hop over bf16 rows ================
// one wave/node; 16 lanes x uint2 (4 bf16) cover 64 feats; 4 edge-groups, 2x unroll.
// EPI: 0 -> bf16 out; 1 -> *vec[node], bf16 out; 2 -> *vec[node]+bias, f32 out
template <int EPI>
__global__ __launch_bounds__(256)
void gather_hop(const uint2* __restrict__ Yin, const int* __restrict__ rowptr,
                const int* __restrict__ csr_src, void* __restrict__ Yout,
                const float* __restrict__ vec, const float* __restrict__ bias,
                int N) {
    int node = blockIdx.x * 4 + ((int)threadIdx.x >> 6);
    int lane = (int)threadIdx.x & 63;
    int g = lane >> 4;
    int ci = lane & 15;
    if (node >= N) return;
    int beg = rowptr[node];
    int end = rowptr[node + 1];
    float4 acc = make_float4(0.f, 0.f, 0.f, 0.f);
    float4 acc2 = make_float4(0.f, 0.f, 0.f, 0.f);
    int k = beg + g;
    for (; k + 4 < end; k += 8) {
        int s0 = csr_src[k];
        int s1 = csr_src[k + 4];
        uint2 v0 = Yin[(size_t)s0 * (OUT_FEATS / 4) + ci];
        uint2 v1 = Yin[(size_t)s1 * (OUT_FEATS / 4) + ci];
        acc.x += bf16_lo(v0.x); acc.y += bf16_hi(v0.x);
        acc.z += bf16_lo(v0.y); acc.w += bf16_hi(v0.y);
        acc2.x += bf16_lo(v1.x); acc2.y += bf16_hi(v1.x);
        acc2.z += bf16_lo(v1.y); acc2.w += bf16_hi(v1.y);
    }
    if (k < end) {
        uint2 v = Yin[(size_t)csr_src[k] * (OUT_FEATS / 4) + ci];
        acc.x += bf16_lo(v.x); acc.y += bf16_hi(v.x);
        acc.z += bf16_lo(v.y); acc.w += bf16_hi(v.y);
    }
    acc.x += acc2.x; acc.y += acc2.y; acc.z += acc2.z; acc.w += acc2.w;
    acc.x += __shfl_xor(acc.x, 16); acc.y += __shfl_xor(acc.y, 16);
    acc.z += __shfl_xor(acc.z, 16); acc.w += __shfl_xor(acc.w, 16);
    acc.x += __shfl_xor(acc.x, 32); acc.y += __shfl_xor(acc.y, 32);
    acc.z += __shfl_xor(acc.z, 32); acc.w += __shfl_xor(acc.w, 32);
    if (g == 0) {
        if (EPI == 1) {
            float sc = vec[node];
            acc.x *= sc; acc.y *= sc; acc.z *= sc; acc.w *= sc;
        }
        if (EPI == 2) {
            float sc = vec[node];
            float4 bb = *reinterpret_cast<const float4*>(bias + ci * 4);
            acc.x = fmaf(acc.x, sc, bb.x); acc.y = fmaf(acc.y, sc, bb.y);
            acc.z = fmaf(acc.z, sc, bb.z); acc.w = fmaf(acc.w, sc, bb.w);
            reinterpret_cast<float4*>(Yout)[(size_t)node * (OUT_FEATS / 4) + ci] = acc;
        } else {
            uint2 o;
            o.x = pack_bf16(acc.x, acc.y);
            o.y = pack_bf16(acc.z, acc.w);
            reinterpret_cast<uint2*>(Yout)[(size_t)node * (OUT_FEATS / 4) + ci] = o;
        }
    }
}

extern "C" void kernel_launch(void* const* d_in, const int* in_sizes, int n_in,
                              void* d_out, int out_size, void* d_ws, size_t ws_size,
                              hipStream_t stream) {
    const float* features = (const float*)d_in[0];
    const int*   src      = (const int*)d_in[1];
    const int*   dst      = (const int*)d_in[2];
    const float* weight   = (const float*)d_in[3];
    const float* bias     = (const float*)d_in[4];

    const int N = in_sizes[0] / IN_FEATS;   // 50000
    const int E = in_sizes[1];              // 640000
    const int words = (N + 1) / 2;          // 25000
    const int NB = (words + PB - 1) / PB;   // 49 (== scan chunk count)
    const int slice_d = (((E + HB_D - 1) / HB_D) + 3) & ~3;  // 5000
    const int slice_s = (((E + HB_S - 1) / HB_S) + 3) & ~3;  // 10000
    const int projBlocks = (N + PROJ_NODES - 1) / PROJ_NODES;

    char* p = (char*)d_ws;
    float* normS   = (float*)p;  p = align_up(p + sizeof(float) * N, 256);
    float* normD   = (float*)p;  p = align_up(p + sizeof(float) * N, 256);
    uint2* y0      = (uint2*)p;  p = align_up(p + sizeof(uint2) * (size_t)N * (OUT_FEATS / 4), 256);
    uint2* y1      = (uint2*)p;  p = align_up(p + sizeof(uint2) * (size_t)N * (OUT_FEATS / 4), 256);
    int*   cntS    = (int*)p;    p = align_up(p + sizeof(int) * (N + 1), 256);
    int*   cntD    = (int*)p;    p = align_up(p + sizeof(int) * (N + 1), 256);
    int*   rowptr  = (int*)p;    p = align_up(p + sizeof(int) * (N + 1), 256);
    int*   bsums   = (int*)p;    p = align_up(p + sizeof(int) * NB, 256);
    int*   csr_src = (int*)p;    p = align_up(p + sizeof(int) * (size_t)E, 256);
    unsigned* partial = (unsigned*)p;  p = align_up(p + sizeof(unsigned) * (size_t)(HB_D + HB_S) * words, 256);
    unsigned* pprefix = (unsigned*)p;  p = align_up(p + sizeof(unsigned) * (size_t)HB_D * words, 256);

    float* out = (float*)d_out;

    // K1: histograms (192 blocks) + projection (391 blocks) run concurrently
    hist_proj_kernel<<<HB_D + HB_S + projBlocks, 1024, 0, stream>>>(
        src, dst, features, weight, partial, y0, N, E, slice_d, slice_s, words);
    // K2: per-word prefixes across dst blocks, counts, chunk sums
    prefix_kernel<<<NB, PB, 0, stream>>>(partial, pprefix, cntS, cntD, bsums, N, words);
    // K3: rowptr + norms (inline scan of chunk sums)
    scan_apply<<<NB, 256, 0, stream>>>(cntD, cntS, bsums, rowptr, normS, normD, N, NB);
    // K4: CSR fill, zero global atomics
    fill_kernel<<<HB_D, 1024, 0, stream>>>(src, dst, pprefix, rowptr, csr_src, E, slice_d, words);

    const int hop_blocks = (N + 3) / 4;
    // hop 1: y1 = A y0                    (bf16 -> bf16)
    gather_hop<0><<<hop_blocks, 256, 0, stream>>>(y0, rowptr, csr_src, (void*)y1, nullptr, nullptr, N);
    // hop 2: y0 = normS .* (A y1)         (bf16 -> bf16)
    gather_hop<1><<<hop_blocks, 256, 0, stream>>>(y1, rowptr, csr_src, (void*)y0, normS, nullptr, N);
    // hop 3: out = normD .* (A y0) + bias (bf16 -> f32)
    gather_hop<2><<<hop_blocks, 256, 0, stream>>>(y0, rowptr, csr_src, (void*)out, normD, bias, N);
}